// Round 3
// baseline (1873.766 us; speedup 1.0000x reference)
//
#include <hip/hip_runtime.h>

// Problem: B=8, H=16, S=1024, D=64, fp32.
// d_out = context[B,H,S,D] (8,388,608 f32) ++ attn[B,H,S,S] (134,217,728 f32).
#define S_ 1024
#define D_ 64
#define CTX_ELEMS (8 * 16 * 1024 * 64)

// ---------------------------------------------------------------------------
// Mask dtype detector (unchanged): writes mode flag to d_ws[0].
// ---------------------------------------------------------------------------
__global__ void detect_mask_kernel(const unsigned int* __restrict__ mask,
                                   int* __restrict__ flag) {
  const int t = threadIdx.x;
  if (t == 0) flag[0] = 0;
  __syncthreads();
  unsigned int local = 0;
  for (int i = t; i < 1024; i += 256) {
    unsigned int w = mask[i];
    if (w == 0x3F800000u)      local |= 2u;   // float 1.0 pattern
    else if (w > 1u)           local |= 1u;   // packed-byte pattern
  }
  if (local) atomicOr(flag, (int)local);
}

// async global->LDS, 16B per lane, LDS dest = wave-uniform base + lane*16.
__device__ __forceinline__ void async_ld16(const float4* g, float* lds) {
  __builtin_amdgcn_global_load_lds(
      (const __attribute__((address_space(1))) void*)g,
      (__attribute__((address_space(3))) void*)lds, 16, 0, 0);
}

// ---------------------------------------------------------------------------
// R3 structure (16-query tile per 256-thread block; acc[4][16] in VGPRs):
//  - K/V staged in 64-row tiles via global_load_lds into LINEAR double-buffered
//    LDS; XOR swizzle (col ^= row&7) applied on the READ side and inverted on
//    the per-lane GLOBAL source (both-sides rule) -> conflict-free ds_read_b128
//    with zero staging VGPRs/VALU. Stage(t+1) issued before compute(t); the
//    end-of-iter __syncthreads drain is covered by the tile's FMAs.
//  - Q read via wave-uniform (readfirstlane) row pointers -> scalar s_load
//    into SGPRs; removes the Qs LDS array and all its broadcast traffic.
//  - Phase 2: lane = (kgroup=l>>4, d4=l&15); reads V[kc*4+kgroup][d4] so each
//    ds_read_b128 fetches 64 DISTINCT float4 (was 4x redundant). Attn coeffs
//    from per-wave transposed AsT[64][20] (one bcast float4 per kc; no
//    cross-wave data -> no extra barriers). 4-way shfl_xor butterfly at end.
//  - Attn global store: per-tile coalesced 256B row stores from acc.
//  - XCD decode: all 64 q-tiles of one bh on one XCD (K/V stay in its L2).
//  - LDS 37.9 KB + VGPR<=128 -> 4 blocks/CU (launch_bounds(256,4)).
// Canary: WRITE_SIZE must stay ~557k KB (attn+ctx only); higher => spill.
// ---------------------------------------------------------------------------
__global__ __launch_bounds__(256, 4)
void attn_fused_kernel(const float* __restrict__ Q, const float* __restrict__ K,
                       const float* __restrict__ V, const void* __restrict__ mask,
                       float* __restrict__ out, const int* __restrict__ flag) {
  __shared__ float KV[2][64][64];   // 32 KB, linear (global_load_lds dest)
  __shared__ float AsT[64][20];     //  5 KB, P^T chunk: AsT[k_local][q] (pad 20)

  const int t  = threadIdx.x;
  const int id = blockIdx.x;                 // 0..8191
  const int xcd  = id & 7;                   // HW round-robins ids over XCDs
  const int slot = id >> 3;                  // 0..1023
  const int bh   = xcd + 8 * (slot >> 6);    // 16 whole bh per XCD
  const int qt   = slot & 63;
  const int q0   = qt * 16;

  const int w = t >> 6;            // wave id = q-group (4 rows)
  const int l = t & 63;            // lane

  const float4* Kb4 = (const float4*)(K + (size_t)bh * (S_ * D_));
  const float4* Vb4 = (const float4*)(V + (size_t)bh * (S_ * D_));

  // Wave-uniform Q row pointers -> compiler emits scalar s_load for Q reads.
  const float* Qrow[4];
  {
    const int wu = __builtin_amdgcn_readfirstlane(w);
#pragma unroll
    for (int qq = 0; qq < 4; ++qq)
      Qrow[qq] = Q + (size_t)bh * (S_ * D_) + (size_t)(q0 + 4 * wu + qq) * D_;
  }

  // Stage one 64x64 f32 tile: 16 instrs/block (4/wave), each 64 lanes x 16B.
  // LDS slot (row r, f4col c') receives global (row r, f4col c' ^ (r&7)).
#define STAGE(src4, tile, buf)                                               \
  {                                                                          \
    _Pragma("unroll")                                                        \
    for (int j = 0; j < 4; ++j) {                                            \
      const int rr = (4 * w + j) * 4 + (l >> 4);                             \
      const int cc = (l & 15) ^ (rr & 7);                                    \
      async_ld16((src4) + ((size_t)((tile) * 64 + rr) * 16 + cc),            \
                 &KV[buf][0][0] + (4 * w + j) * 256);                        \
    }                                                                        \
  }

  STAGE(Kb4, 0, 0);

  float acc[4][16];
#pragma unroll
  for (int qq = 0; qq < 4; ++qq)
#pragma unroll
    for (int ci = 0; ci < 16; ++ci) acc[qq][ci] = 0.f;

  __syncthreads();                           // K tile 0 resident

  // ---- Phase 1: scores = Q K^T (16 tiles of 64 k-rows; ci == kt) ----
#pragma unroll
  for (int kt = 0; kt < 16; ++kt) {
    if (kt < 15) { STAGE(Kb4, kt + 1, (kt + 1) & 1); }
    else         { STAGE(Vb4, 0, 0); }       // V tile 0 -> buf (15+1)&1 == 0
#pragma unroll 4
    for (int d4 = 0; d4 < 16; ++d4) {
      const float4 kv = *(const float4*)&KV[kt & 1][l][(d4 ^ (l & 7)) << 2];
#pragma unroll
      for (int qq = 0; qq < 4; ++qq) {
        const float4 qv = *(const float4*)(Qrow[qq] + (d4 << 2));  // SGPR data
        acc[qq][kt] += qv.x * kv.x + qv.y * kv.y + qv.z * kv.z + qv.w * kv.w;
      }
    }
    __syncthreads();                         // drains next-tile stage too
  }

  // ---- mask + scale (wave-uniform mode branch; k = 64*ci + l) ----
  const float scale = 0.125f;                // 1/sqrt(64)
  const int mode = *flag;
  const size_t mbase = (size_t)bh * ((size_t)S_ * S_) + (size_t)q0 * S_;
  if (mode & 2) {                            // float32 mask
    const float* mf = (const float*)mask + mbase;
#pragma unroll
    for (int qq = 0; qq < 4; ++qq) {
      const float* mr = mf + (4 * w + qq) * S_ + l;
#pragma unroll
      for (int ci = 0; ci < 16; ++ci)
        acc[qq][ci] = (mr[64 * ci] != 0.f) ? -1e9f : acc[qq][ci] * scale;
    }
  } else if (mode & 1) {                     // uint8 mask
    const unsigned char* mu = (const unsigned char*)mask + mbase;
#pragma unroll
    for (int qq = 0; qq < 4; ++qq) {
      const unsigned char* mr = mu + (4 * w + qq) * S_ + l;
#pragma unroll
      for (int ci = 0; ci < 16; ++ci)
        acc[qq][ci] = mr[64 * ci] ? -1e9f : acc[qq][ci] * scale;
    }
  } else {                                   // int32 mask
    const int* mi = (const int*)mask + mbase;
#pragma unroll
    for (int qq = 0; qq < 4; ++qq) {
      const int* mr = mi + (4 * w + qq) * S_ + l;
#pragma unroll
      for (int ci = 0; ci < 16; ++ci)
        acc[qq][ci] = mr[64 * ci] ? -1e9f : acc[qq][ci] * scale;
    }
  }

  // ---- softmax per row: full-wave shuffle reductions (no stores here) ----
#pragma unroll
  for (int qq = 0; qq < 4; ++qq) {
    float mx = -3.4e38f;
#pragma unroll
    for (int ci = 0; ci < 16; ++ci) mx = fmaxf(mx, acc[qq][ci]);
#pragma unroll
    for (int off = 32; off > 0; off >>= 1) mx = fmaxf(mx, __shfl_xor(mx, off, 64));
    float sum = 0.f;
#pragma unroll
    for (int ci = 0; ci < 16; ++ci) {
      const float p = __expf(acc[qq][ci] - mx);  // all-masked row -> uniform, matches ref
      acc[qq][ci] = p;
      sum += p;
    }
#pragma unroll
    for (int off = 32; off > 0; off >>= 1) sum += __shfl_xor(sum, off, 64);
    const float inv = 1.0f / sum;
#pragma unroll
    for (int ci = 0; ci < 16; ++ci) acc[qq][ci] *= inv;
  }

  // ---- Phase 2: context = attn @ V (V tile 0 already resident in KV[0]) ----
  float* outAttn = out + CTX_ELEMS;
  const int d4B = l & 15;        // float4 column of D
  const int kg  = l >> 4;        // k-group: lane covers k == kg (mod 4)
  float4 cacc[4];
#pragma unroll
  for (int qq = 0; qq < 4; ++qq) { cacc[qq].x = cacc[qq].y = cacc[qq].z = cacc[qq].w = 0.f; }

#pragma unroll
  for (int vt = 0; vt < 16; ++vt) {
    if (vt < 15) { STAGE(Vb4, vt + 1, (vt + 1) & 1); }
    // dump P^T chunk (per-wave columns; within-wave use only -> no barrier)
    // + coalesced attn row stores (256B per wave per row)
#pragma unroll
    for (int qq = 0; qq < 4; ++qq) {
      AsT[l][4 * w + qq] = acc[qq][vt];
      outAttn[mbase + (size_t)(4 * w + qq) * S_ + vt * 64 + l] = acc[qq][vt];
    }
#pragma unroll 4
    for (int kc = 0; kc < 16; ++kc) {
      const int krow = kc * 4 + kg;
      const float4 av = *(const float4*)&AsT[krow][4 * w];   // a[qq], 4-addr bcast
      const float4 vv = *(const float4*)&KV[vt & 1][krow][(d4B ^ (krow & 7)) << 2];
      cacc[0].x += av.x * vv.x; cacc[0].y += av.x * vv.y; cacc[0].z += av.x * vv.z; cacc[0].w += av.x * vv.w;
      cacc[1].x += av.y * vv.x; cacc[1].y += av.y * vv.y; cacc[1].z += av.y * vv.z; cacc[1].w += av.y * vv.w;
      cacc[2].x += av.z * vv.x; cacc[2].y += av.z * vv.y; cacc[2].z += av.z * vv.z; cacc[2].w += av.z * vv.w;
      cacc[3].x += av.w * vv.x; cacc[3].y += av.w * vv.y; cacc[3].z += av.w * vv.z; cacc[3].w += av.w * vv.w;
    }
    __syncthreads();                         // KV buffer handoff
  }

  // ---- butterfly-reduce the 4 k-groups; lanes 0..15 hold all 16 d4 cols ----
#pragma unroll
  for (int qq = 0; qq < 4; ++qq) {
    cacc[qq].x += __shfl_xor(cacc[qq].x, 16, 64);
    cacc[qq].y += __shfl_xor(cacc[qq].y, 16, 64);
    cacc[qq].z += __shfl_xor(cacc[qq].z, 16, 64);
    cacc[qq].w += __shfl_xor(cacc[qq].w, 16, 64);
    cacc[qq].x += __shfl_xor(cacc[qq].x, 32, 64);
    cacc[qq].y += __shfl_xor(cacc[qq].y, 32, 64);
    cacc[qq].z += __shfl_xor(cacc[qq].z, 32, 64);
    cacc[qq].w += __shfl_xor(cacc[qq].w, 32, 64);
  }
  if (l < 16) {
    float* ctx = out + (size_t)bh * (S_ * D_);
#pragma unroll
    for (int qq = 0; qq < 4; ++qq)
      ((float4*)(ctx + (size_t)(q0 + 4 * w + qq) * D_))[l] = cacc[qq];
  }
#undef STAGE
}

extern "C" void kernel_launch(void* const* d_in, const int* in_sizes, int n_in,
                              void* d_out, int out_size, void* d_ws, size_t ws_size,
                              hipStream_t stream) {
  const float* Q = (const float*)d_in[0];
  const float* K = (const float*)d_in[1];
  const float* V = (const float*)d_in[2];
  const void* mask = d_in[3];
  int* flag = (int*)d_ws;

  detect_mask_kernel<<<1, 256, 0, stream>>>((const unsigned int*)mask, flag);

  dim3 grid(64 * 128);   // 1D; XCD-aware decode inside the kernel
  attn_fused_kernel<<<grid, 256, 0, stream>>>(Q, K, V, mask, (float*)d_out, flag);
}